// Round 5
// baseline (1323.267 us; speedup 1.0000x reference)
//
#include <hip/hip_runtime.h>
#include <hip/hip_bf16.h>

#define C_CH 32
#define K_TAPS 27
#define CONV_GRID 8192

typedef short bf16x8 __attribute__((ext_vector_type(8)));
typedef float f32x4 __attribute__((ext_vector_type(4)));

// ---------------------------------------------------------------------------
// Kernel 0a: weights f32 -> bf16 MFMA B-fragments (layout verified r3/r4).
// Element t: e=t&7, lane=(t>>3)&63, half=(t>>9)&1, tap=t>>10.
// B[k=ci][n=j]: ci=(lane>>4)*8+e, j=half*16+(lane&15).
// ---------------------------------------------------------------------------
__global__ __launch_bounds__(256) void convert_weights_kernel(
    const float* __restrict__ wt, short* __restrict__ wbf)
{
    int t = blockIdx.x * 256 + threadIdx.x;
    if (t < K_TAPS * 1024) {
        int e = t & 7, l = (t >> 3) & 63, half = (t >> 9) & 1, k = t >> 10;
        int ci = (l >> 4) * 8 + e;
        int j  = half * 16 + (l & 15);
        union { __hip_bfloat16 h; short s; } u;
        u.h = __float2bfloat16(wt[k * 1024 + ci * 32 + j]);
        wbf[t] = u.s;
    }
}

// ---------------------------------------------------------------------------
// Kernel 0b: features f32 -> bf16 table [N][32] (row = 64 B).
// Each thread converts 8 elements (2x float4 -> 1x bf16x8 store).
// ---------------------------------------------------------------------------
__global__ __launch_bounds__(256) void convert_feat_kernel(
    const float* __restrict__ feat, short* __restrict__ featb, int total8)
{
    int t = blockIdx.x * 256 + threadIdx.x;
    if (t < total8) {
        const float4* p = (const float4*)(feat + (size_t)t * 8);
        float4 a = p[0], b = p[1];
        union { bf16x8 v; __hip_bfloat162 h[4]; } u;
        u.h[0] = __float22bfloat162_rn(make_float2(a.x, a.y));
        u.h[1] = __float22bfloat162_rn(make_float2(a.z, a.w));
        u.h[2] = __float22bfloat162_rn(make_float2(b.x, b.y));
        u.h[3] = __float22bfloat162_rn(make_float2(b.z, b.w));
        ((bf16x8*)featb)[t] = u.v;
    }
}

// ---------------------------------------------------------------------------
// Kernel 1: sparse conv via MFMA over a PRE-CONVERTED bf16 feature table.
// One wave = 16 voxels. Per tap: ONE 16B gather/lane (directly the MFMA
// A-fragment), 2 weight fragment loads (L2-resident), 2 MFMAs.
// Unconditional straight-line 27-tap body; invalid taps masked by cndmask.
// launch_bounds(256,5) caps VGPR at ~102 so hoist-depth can't kill occupancy.
// ---------------------------------------------------------------------------
__global__ __launch_bounds__(256, 5) void conv_mfma_kernel(
    const short* __restrict__ featb,  // [N][32] bf16
    const short* __restrict__ wbf,    // bf16 B-fragments [27][2][64][8]
    const int*   __restrict__ nbr,    // [N, 27]
    float* __restrict__ out,          // [N, 32] (pre-BN)
    float* __restrict__ stats,        // [0..31] sum, [32..63] sumsq
    int n)
{
    __shared__ float bsum[C_CH];
    __shared__ float bsq[C_CH];
    const int tid = threadIdx.x;
    if (tid < C_CH) { bsum[tid] = 0.0f; bsq[tid] = 0.0f; }
    __syncthreads();

    const int l   = tid & 63;
    const int wv  = tid >> 6;
    const int row = l & 15;        // A-row / voxel slot within batch
    const int kq  = l >> 4;        // k-chunk 0..3

    // XCD-chunked bijective swizzle (CONV_GRID % 8 == 0): consecutive work
    // blocks land on the SAME XCD so the gather's diagonal band stays in
    // that XCD's L2.
    const int bid  = blockIdx.x;
    const int sbid = (bid & 7) * (CONV_GRID / 8) + (bid >> 3);

    const int n_batches   = (n + 15) >> 4;
    const int wave_gid    = sbid * 4 + wv;
    const int total_waves = CONV_GRID * 4;

    float ps0 = 0.0f, ps1 = 0.0f, pq0 = 0.0f, pq1 = 0.0f;

    for (int b = wave_gid; b < n_batches; b += total_waves) {
        const int vbase = b << 4;
        const int myv   = vbase + row;
        const bool rowok = myv < n;
        const size_t ibase = (size_t)myv * K_TAPS;

        f32x4 acc0 = {0.f, 0.f, 0.f, 0.f};
        f32x4 acc1 = {0.f, 0.f, 0.f, 0.f};

        #pragma unroll
        for (int k = 0; k < K_TAPS; ++k) {
            const int  idx   = rowok ? nbr[ibase + k] : -1;
            const bool valid = idx >= 0;
            const int  safe  = valid ? idx : 0;

            // 16B gather = the A-fragment (lanes r,r+16,r+32,r+48 cover the
            // 64B row of voxel-slot r -> coalesced 64B transactions)
            bf16x8 a = *(const bf16x8*)(featb + ((size_t)safe << 5) + (kq << 3));
            const bf16x8 zero = {0, 0, 0, 0, 0, 0, 0, 0};
            a = valid ? a : zero;                    // 4x v_cndmask_b32

            bf16x8 b0 = *(const bf16x8*)(wbf + (((k * 2 + 0) * 64 + l) << 3));
            bf16x8 b1 = *(const bf16x8*)(wbf + (((k * 2 + 1) * 64 + l) << 3));

            acc0 = __builtin_amdgcn_mfma_f32_16x16x32_bf16(a, b0, acc0, 0, 0, 0);
            acc1 = __builtin_amdgcn_mfma_f32_16x16x32_bf16(a, b1, acc1, 0, 0, 0);
        }

        // C/D layout: col = lane&15, row = (lane>>4)*4 + r
        #pragma unroll
        for (int r = 0; r < 4; ++r) {
            const int orow = vbase + kq * 4 + r;
            if (orow < n) {
                const float v0 = acc0[r];
                const float v1 = acc1[r];
                out[(size_t)orow * C_CH + (l & 15)]      = v0;
                out[(size_t)orow * C_CH + 16 + (l & 15)] = v1;
                ps0 += v0; pq0 += v0 * v0;
                ps1 += v1; pq1 += v1 * v1;
            }
        }
    }

    // lanes {l, l^16, l^32, l^48} hold the same channel pair -> combine
    ps0 += __shfl_xor(ps0, 16); ps0 += __shfl_xor(ps0, 32);
    ps1 += __shfl_xor(ps1, 16); ps1 += __shfl_xor(ps1, 32);
    pq0 += __shfl_xor(pq0, 16); pq0 += __shfl_xor(pq0, 32);
    pq1 += __shfl_xor(pq1, 16); pq1 += __shfl_xor(pq1, 32);

    if (l < 16) {
        atomicAdd(&bsum[l],      ps0);
        atomicAdd(&bsum[16 + l], ps1);
        atomicAdd(&bsq[l],       pq0);
        atomicAdd(&bsq[16 + l],  pq1);
    }
    __syncthreads();
    if (tid < C_CH) {
        atomicAdd(&stats[tid],        bsum[tid]);
        atomicAdd(&stats[C_CH + tid], bsq[tid]);
    }
}

// ---------------------------------------------------------------------------
// Kernel 1-fallback (ws too small for bf16 feature table): round-3-style
// in-kernel conversion path, with swizzle.
// ---------------------------------------------------------------------------
__global__ __launch_bounds__(256, 5) void conv_mfma_f32_kernel(
    const float* __restrict__ feat,
    const short* __restrict__ wbf,
    const int*   __restrict__ nbr,
    float* __restrict__ out,
    float* __restrict__ stats,
    int n)
{
    __shared__ float bsum[C_CH];
    __shared__ float bsq[C_CH];
    const int tid = threadIdx.x;
    if (tid < C_CH) { bsum[tid] = 0.0f; bsq[tid] = 0.0f; }
    __syncthreads();

    const int l   = tid & 63;
    const int wv  = tid >> 6;
    const int row = l & 15;
    const int kq  = l >> 4;
    const int bid  = blockIdx.x;
    const int sbid = (bid & 7) * (CONV_GRID / 8) + (bid >> 3);
    const int n_batches   = (n + 15) >> 4;
    const int wave_gid    = sbid * 4 + wv;
    const int total_waves = CONV_GRID * 4;

    float ps0 = 0.0f, ps1 = 0.0f, pq0 = 0.0f, pq1 = 0.0f;

    for (int b = wave_gid; b < n_batches; b += total_waves) {
        const int vbase = b << 4;
        const int myv   = vbase + row;
        const bool rowok = myv < n;
        const size_t ibase = (size_t)myv * K_TAPS;

        f32x4 acc0 = {0.f, 0.f, 0.f, 0.f};
        f32x4 acc1 = {0.f, 0.f, 0.f, 0.f};

        #pragma unroll
        for (int k = 0; k < K_TAPS; ++k) {
            const int  idx   = rowok ? nbr[ibase + k] : -1;
            const bool valid = idx >= 0;
            const int  safe  = valid ? idx : 0;

            const float4* fp = (const float4*)(feat + (size_t)safe * C_CH + kq * 8);
            float4 f0 = fp[0];
            float4 f1 = fp[1];
            union { bf16x8 v; __hip_bfloat162 h[4]; } au;
            au.h[0] = __float22bfloat162_rn(make_float2(f0.x, f0.y));
            au.h[1] = __float22bfloat162_rn(make_float2(f0.z, f0.w));
            au.h[2] = __float22bfloat162_rn(make_float2(f1.x, f1.y));
            au.h[3] = __float22bfloat162_rn(make_float2(f1.z, f1.w));
            const bf16x8 zero = {0, 0, 0, 0, 0, 0, 0, 0};
            bf16x8 a = valid ? au.v : zero;

            bf16x8 b0 = *(const bf16x8*)(wbf + (((k * 2 + 0) * 64 + l) << 3));
            bf16x8 b1 = *(const bf16x8*)(wbf + (((k * 2 + 1) * 64 + l) << 3));

            acc0 = __builtin_amdgcn_mfma_f32_16x16x32_bf16(a, b0, acc0, 0, 0, 0);
            acc1 = __builtin_amdgcn_mfma_f32_16x16x32_bf16(a, b1, acc1, 0, 0, 0);
        }

        #pragma unroll
        for (int r = 0; r < 4; ++r) {
            const int orow = vbase + kq * 4 + r;
            if (orow < n) {
                const float v0 = acc0[r];
                const float v1 = acc1[r];
                out[(size_t)orow * C_CH + (l & 15)]      = v0;
                out[(size_t)orow * C_CH + 16 + (l & 15)] = v1;
                ps0 += v0; pq0 += v0 * v0;
                ps1 += v1; pq1 += v1 * v1;
            }
        }
    }

    ps0 += __shfl_xor(ps0, 16); ps0 += __shfl_xor(ps0, 32);
    ps1 += __shfl_xor(ps1, 16); ps1 += __shfl_xor(ps1, 32);
    pq0 += __shfl_xor(pq0, 16); pq0 += __shfl_xor(pq0, 32);
    pq1 += __shfl_xor(pq1, 16); pq1 += __shfl_xor(pq1, 32);

    if (l < 16) {
        atomicAdd(&bsum[l],      ps0);
        atomicAdd(&bsum[16 + l], ps1);
        atomicAdd(&bsq[l],       pq0);
        atomicAdd(&bsq[16 + l],  pq1);
    }
    __syncthreads();
    if (tid < C_CH) {
        atomicAdd(&stats[tid],        bsum[tid]);
        atomicAdd(&stats[C_CH + tid], bsq[tid]);
    }
}

// ---------------------------------------------------------------------------
// Kernel 2: BN finalize (per-block, into LDS) + apply + ReLU, float4 in-place
// ---------------------------------------------------------------------------
__global__ __launch_bounds__(256) void bn_apply_kernel(
    float* __restrict__ out,
    const float* __restrict__ stats,
    const float* __restrict__ gamma,
    const float* __restrict__ beta,
    float inv_n, int total4)
{
    __shared__ float s_sc[C_CH];
    __shared__ float s_sh[C_CH];
    if (threadIdx.x < C_CH) {
        int j = threadIdx.x;
        float mean = stats[j] * inv_n;
        float var  = stats[C_CH + j] * inv_n - mean * mean;
        float sc   = gamma[j] * rsqrtf(var + 1e-4f);
        s_sc[j] = sc;
        s_sh[j] = beta[j] - mean * sc;
    }
    __syncthreads();

    int e = blockIdx.x * 256 + threadIdx.x;
    if (e < total4) {
        float4 v = ((float4*)out)[e];
        int c = (e & 7) * 4;
        v.x = fmaxf(fmaf(v.x, s_sc[c + 0], s_sh[c + 0]), 0.0f);
        v.y = fmaxf(fmaf(v.y, s_sc[c + 1], s_sh[c + 1]), 0.0f);
        v.z = fmaxf(fmaf(v.z, s_sc[c + 2], s_sh[c + 2]), 0.0f);
        v.w = fmaxf(fmaf(v.w, s_sc[c + 3], s_sh[c + 3]), 0.0f);
        ((float4*)out)[e] = v;
    }
}

extern "C" void kernel_launch(void* const* d_in, const int* in_sizes, int n_in,
                              void* d_out, int out_size, void* d_ws, size_t ws_size,
                              hipStream_t stream) {
    const float* feat  = (const float*)d_in[0];   // [N, 32]
    const float* wt    = (const float*)d_in[1];   // [27, 32, 32]
    const float* gamma = (const float*)d_in[2];   // [32]
    const float* beta  = (const float*)d_in[3];   // [32]
    const int*   nbr   = (const int*)d_in[4];     // [N, 27]

    float* out   = (float*)d_out;
    float* stats = (float*)d_ws;                    // 64 f32: sum, sumsq
    short* wbf   = (short*)(stats + 2 * C_CH);      // 27648 bf16 weight frags
    short* featb = wbf + K_TAPS * 1024;             // [N][32] bf16 table

    const int n = in_sizes[0] / C_CH;
    const size_t need = 2 * C_CH * sizeof(float) + K_TAPS * 1024 * sizeof(short)
                      + (size_t)n * C_CH * sizeof(short);

    hipMemsetAsync(stats, 0, 2 * C_CH * sizeof(float), stream);

    convert_weights_kernel<<<(K_TAPS * 1024 + 255) / 256, 256, 0, stream>>>(wt, wbf);

    if (ws_size >= need) {
        const int total8 = n * C_CH / 8;
        convert_feat_kernel<<<(total8 + 255) / 256, 256, 0, stream>>>(
            feat, featb, total8);
        conv_mfma_kernel<<<CONV_GRID, 256, 0, stream>>>(
            featb, wbf, nbr, out, stats, n);
    } else {
        conv_mfma_f32_kernel<<<CONV_GRID, 256, 0, stream>>>(
            feat, wbf, nbr, out, stats, n);
    }

    const int total4 = n * C_CH / 4;
    bn_apply_kernel<<<(total4 + 255) / 256, 256, 0, stream>>>(
        out, stats, gamma, beta, 1.0f / (float)n, total4);
}

// Round 6
// 1087.641 us; speedup vs baseline: 1.2166x; 1.2166x over previous
//
#include <hip/hip_runtime.h>
#include <hip/hip_bf16.h>

#define C_CH 32
#define K_TAPS 27
#define CONV_GRID 8192

typedef short bf16x8 __attribute__((ext_vector_type(8)));
typedef float f32x4 __attribute__((ext_vector_type(4)));

// ---------------------------------------------------------------------------
// Kernel 0a: weights f32 -> bf16 MFMA B-fragments (layout verified r3/r4).
// Element t: e=t&7, lane=(t>>3)&63, half=(t>>9)&1, tap=t>>10.
// B[k=ci][n=j]: ci=(lane>>4)*8+e, j=half*16+(lane&15).
// ---------------------------------------------------------------------------
__global__ __launch_bounds__(256) void convert_weights_kernel(
    const float* __restrict__ wt, short* __restrict__ wbf)
{
    int t = blockIdx.x * 256 + threadIdx.x;
    if (t < K_TAPS * 1024) {
        int e = t & 7, l = (t >> 3) & 63, half = (t >> 9) & 1, k = t >> 10;
        int ci = (l >> 4) * 8 + e;
        int j  = half * 16 + (l & 15);
        union { __hip_bfloat16 h; short s; } u;
        u.h = __float2bfloat16(wt[k * 1024 + ci * 32 + j]);
        wbf[t] = u.s;
    }
}

// ---------------------------------------------------------------------------
// Kernel 0b: features f32 -> bf16 table [N][32] (row = 64 B).
// ---------------------------------------------------------------------------
__global__ __launch_bounds__(256) void convert_feat_kernel(
    const float* __restrict__ feat, short* __restrict__ featb, int total8)
{
    int t = blockIdx.x * 256 + threadIdx.x;
    if (t < total8) {
        const float4* p = (const float4*)(feat + (size_t)t * 8);
        float4 a = p[0], b = p[1];
        union { bf16x8 v; __hip_bfloat162 h[4]; } u;
        u.h[0] = __float22bfloat162_rn(make_float2(a.x, a.y));
        u.h[1] = __float22bfloat162_rn(make_float2(a.z, a.w));
        u.h[2] = __float22bfloat162_rn(make_float2(b.x, b.y));
        u.h[3] = __float22bfloat162_rn(make_float2(b.z, b.w));
        ((bf16x8*)featb)[t] = u.v;
    }
}

// ---------------------------------------------------------------------------
// Kernel 1: sparse conv via MFMA over pre-converted bf16 feature table.
// One wave = 16 voxels/batch, 2 CONSECUTIVE batches per wave.
// Per tap: ONE 16B gather/lane (directly the MFMA A-fragment), 2 weight
// fragment loads (L2-resident), 2 MFMAs. Unconditional straight-line body.
// IDENTITY block mapping: r5's XCD swizzle caused 8-11x cache-thrash
// amplification (FETCH 175MB->1.35GB) — concurrent blocks already form a
// contiguous voxel window whose gather band is L2/L3-resident.
// launch_bounds(256,4): cap 128 VGPR -> hoist depth ~12 gathers AND >=4
// waves/SIMD.
// ---------------------------------------------------------------------------
__global__ __launch_bounds__(256, 4) void conv_mfma_kernel(
    const short* __restrict__ featb,  // [N][32] bf16
    const short* __restrict__ wbf,    // bf16 B-fragments [27][2][64][8]
    const int*   __restrict__ nbr,    // [N, 27]
    float* __restrict__ out,          // [N, 32] (pre-BN)
    float* __restrict__ stats,        // [0..31] sum, [32..63] sumsq
    int n)
{
    __shared__ float bsum[C_CH];
    __shared__ float bsq[C_CH];
    const int tid = threadIdx.x;
    if (tid < C_CH) { bsum[tid] = 0.0f; bsq[tid] = 0.0f; }
    __syncthreads();

    const int l   = tid & 63;
    const int wv  = tid >> 6;
    const int row = l & 15;        // A-row / voxel slot within batch
    const int kq  = l >> 4;        // k-chunk 0..3

    const int n_batches   = (n + 15) >> 4;
    const int wave_gid    = blockIdx.x * 4 + wv;
    const int total_waves = CONV_GRID * 4;

    float ps0 = 0.0f, ps1 = 0.0f, pq0 = 0.0f, pq1 = 0.0f;

    for (int bb = wave_gid * 2; bb < n_batches; bb += total_waves * 2) {
        const int bend = (bb + 2 < n_batches) ? bb + 2 : n_batches;
        for (int b = bb; b < bend; ++b) {
            const int vbase = b << 4;
            const int myv   = vbase + row;
            const bool rowok = myv < n;
            const size_t ibase = (size_t)myv * K_TAPS;

            f32x4 acc0 = {0.f, 0.f, 0.f, 0.f};
            f32x4 acc1 = {0.f, 0.f, 0.f, 0.f};

            #pragma unroll
            for (int k = 0; k < K_TAPS; ++k) {
                const int  idx   = rowok ? nbr[ibase + k] : -1;
                const bool valid = idx >= 0;
                const int  safe  = valid ? idx : 0;

                // 16B gather = the A-fragment (lanes r,r+16,r+32,r+48 cover
                // the 64B row of voxel-slot r -> 64B transactions)
                bf16x8 a = *(const bf16x8*)(featb + ((size_t)safe << 5) + (kq << 3));
                const bf16x8 zero = {0, 0, 0, 0, 0, 0, 0, 0};
                a = valid ? a : zero;                    // 4x v_cndmask_b32

                bf16x8 b0 = *(const bf16x8*)(wbf + (((k * 2 + 0) * 64 + l) << 3));
                bf16x8 b1 = *(const bf16x8*)(wbf + (((k * 2 + 1) * 64 + l) << 3));

                acc0 = __builtin_amdgcn_mfma_f32_16x16x32_bf16(a, b0, acc0, 0, 0, 0);
                acc1 = __builtin_amdgcn_mfma_f32_16x16x32_bf16(a, b1, acc1, 0, 0, 0);
            }

            // C/D layout: col = lane&15, row = (lane>>4)*4 + r
            #pragma unroll
            for (int r = 0; r < 4; ++r) {
                const int orow = vbase + kq * 4 + r;
                if (orow < n) {
                    const float v0 = acc0[r];
                    const float v1 = acc1[r];
                    out[(size_t)orow * C_CH + (l & 15)]      = v0;
                    out[(size_t)orow * C_CH + 16 + (l & 15)] = v1;
                    ps0 += v0; pq0 += v0 * v0;
                    ps1 += v1; pq1 += v1 * v1;
                }
            }
        }
    }

    // lanes {l, l^16, l^32, l^48} hold the same channel pair -> combine
    ps0 += __shfl_xor(ps0, 16); ps0 += __shfl_xor(ps0, 32);
    ps1 += __shfl_xor(ps1, 16); ps1 += __shfl_xor(ps1, 32);
    pq0 += __shfl_xor(pq0, 16); pq0 += __shfl_xor(pq0, 32);
    pq1 += __shfl_xor(pq1, 16); pq1 += __shfl_xor(pq1, 32);

    if (l < 16) {
        atomicAdd(&bsum[l],      ps0);
        atomicAdd(&bsum[16 + l], ps1);
        atomicAdd(&bsq[l],       pq0);
        atomicAdd(&bsq[16 + l],  pq1);
    }
    __syncthreads();
    if (tid < C_CH) {
        atomicAdd(&stats[tid],        bsum[tid]);
        atomicAdd(&stats[C_CH + tid], bsq[tid]);
    }
}

// ---------------------------------------------------------------------------
// Kernel 1-fallback (ws too small for bf16 feature table): in-kernel cvt.
// ---------------------------------------------------------------------------
__global__ __launch_bounds__(256, 4) void conv_mfma_f32_kernel(
    const float* __restrict__ feat,
    const short* __restrict__ wbf,
    const int*   __restrict__ nbr,
    float* __restrict__ out,
    float* __restrict__ stats,
    int n)
{
    __shared__ float bsum[C_CH];
    __shared__ float bsq[C_CH];
    const int tid = threadIdx.x;
    if (tid < C_CH) { bsum[tid] = 0.0f; bsq[tid] = 0.0f; }
    __syncthreads();

    const int l   = tid & 63;
    const int wv  = tid >> 6;
    const int row = l & 15;
    const int kq  = l >> 4;
    const int n_batches   = (n + 15) >> 4;
    const int wave_gid    = blockIdx.x * 4 + wv;
    const int total_waves = CONV_GRID * 4;

    float ps0 = 0.0f, ps1 = 0.0f, pq0 = 0.0f, pq1 = 0.0f;

    for (int b = wave_gid; b < n_batches; b += total_waves) {
        const int vbase = b << 4;
        const int myv   = vbase + row;
        const bool rowok = myv < n;
        const size_t ibase = (size_t)myv * K_TAPS;

        f32x4 acc0 = {0.f, 0.f, 0.f, 0.f};
        f32x4 acc1 = {0.f, 0.f, 0.f, 0.f};

        #pragma unroll
        for (int k = 0; k < K_TAPS; ++k) {
            const int  idx   = rowok ? nbr[ibase + k] : -1;
            const bool valid = idx >= 0;
            const int  safe  = valid ? idx : 0;

            const float4* fp = (const float4*)(feat + (size_t)safe * C_CH + kq * 8);
            float4 f0 = fp[0];
            float4 f1 = fp[1];
            union { bf16x8 v; __hip_bfloat162 h[4]; } au;
            au.h[0] = __float22bfloat162_rn(make_float2(f0.x, f0.y));
            au.h[1] = __float22bfloat162_rn(make_float2(f0.z, f0.w));
            au.h[2] = __float22bfloat162_rn(make_float2(f1.x, f1.y));
            au.h[3] = __float22bfloat162_rn(make_float2(f1.z, f1.w));
            const bf16x8 zero = {0, 0, 0, 0, 0, 0, 0, 0};
            bf16x8 a = valid ? au.v : zero;

            bf16x8 b0 = *(const bf16x8*)(wbf + (((k * 2 + 0) * 64 + l) << 3));
            bf16x8 b1 = *(const bf16x8*)(wbf + (((k * 2 + 1) * 64 + l) << 3));

            acc0 = __builtin_amdgcn_mfma_f32_16x16x32_bf16(a, b0, acc0, 0, 0, 0);
            acc1 = __builtin_amdgcn_mfma_f32_16x16x32_bf16(a, b1, acc1, 0, 0, 0);
        }

        #pragma unroll
        for (int r = 0; r < 4; ++r) {
            const int orow = vbase + kq * 4 + r;
            if (orow < n) {
                const float v0 = acc0[r];
                const float v1 = acc1[r];
                out[(size_t)orow * C_CH + (l & 15)]      = v0;
                out[(size_t)orow * C_CH + 16 + (l & 15)] = v1;
                ps0 += v0; pq0 += v0 * v0;
                ps1 += v1; pq1 += v1 * v1;
            }
        }
    }

    ps0 += __shfl_xor(ps0, 16); ps0 += __shfl_xor(ps0, 32);
    ps1 += __shfl_xor(ps1, 16); ps1 += __shfl_xor(ps1, 32);
    pq0 += __shfl_xor(pq0, 16); pq0 += __shfl_xor(pq0, 32);
    pq1 += __shfl_xor(pq1, 16); pq1 += __shfl_xor(pq1, 32);

    if (l < 16) {
        atomicAdd(&bsum[l],      ps0);
        atomicAdd(&bsum[16 + l], ps1);
        atomicAdd(&bsq[l],       pq0);
        atomicAdd(&bsq[16 + l],  pq1);
    }
    __syncthreads();
    if (tid < C_CH) {
        atomicAdd(&stats[tid],        bsum[tid]);
        atomicAdd(&stats[C_CH + tid], bsq[tid]);
    }
}

// ---------------------------------------------------------------------------
// Kernel 2: BN finalize (per-block, into LDS) + apply + ReLU, float4 in-place
// ---------------------------------------------------------------------------
__global__ __launch_bounds__(256) void bn_apply_kernel(
    float* __restrict__ out,
    const float* __restrict__ stats,
    const float* __restrict__ gamma,
    const float* __restrict__ beta,
    float inv_n, int total4)
{
    __shared__ float s_sc[C_CH];
    __shared__ float s_sh[C_CH];
    if (threadIdx.x < C_CH) {
        int j = threadIdx.x;
        float mean = stats[j] * inv_n;
        float var  = stats[C_CH + j] * inv_n - mean * mean;
        float sc   = gamma[j] * rsqrtf(var + 1e-4f);
        s_sc[j] = sc;
        s_sh[j] = beta[j] - mean * sc;
    }
    __syncthreads();

    int e = blockIdx.x * 256 + threadIdx.x;
    if (e < total4) {
        float4 v = ((float4*)out)[e];
        int c = (e & 7) * 4;
        v.x = fmaxf(fmaf(v.x, s_sc[c + 0], s_sh[c + 0]), 0.0f);
        v.y = fmaxf(fmaf(v.y, s_sc[c + 1], s_sh[c + 1]), 0.0f);
        v.z = fmaxf(fmaf(v.z, s_sc[c + 2], s_sh[c + 2]), 0.0f);
        v.w = fmaxf(fmaf(v.w, s_sc[c + 3], s_sh[c + 3]), 0.0f);
        ((float4*)out)[e] = v;
    }
}

extern "C" void kernel_launch(void* const* d_in, const int* in_sizes, int n_in,
                              void* d_out, int out_size, void* d_ws, size_t ws_size,
                              hipStream_t stream) {
    const float* feat  = (const float*)d_in[0];   // [N, 32]
    const float* wt    = (const float*)d_in[1];   // [27, 32, 32]
    const float* gamma = (const float*)d_in[2];   // [32]
    const float* beta  = (const float*)d_in[3];   // [32]
    const int*   nbr   = (const int*)d_in[4];     // [N, 27]

    float* out   = (float*)d_out;
    float* stats = (float*)d_ws;                    // 64 f32: sum, sumsq
    short* wbf   = (short*)(stats + 2 * C_CH);      // 27648 bf16 weight frags
    short* featb = wbf + K_TAPS * 1024;             // [N][32] bf16 table

    const int n = in_sizes[0] / C_CH;
    const size_t need = 2 * C_CH * sizeof(float) + K_TAPS * 1024 * sizeof(short)
                      + (size_t)n * C_CH * sizeof(short);

    hipMemsetAsync(stats, 0, 2 * C_CH * sizeof(float), stream);

    convert_weights_kernel<<<(K_TAPS * 1024 + 255) / 256, 256, 0, stream>>>(wt, wbf);

    if (ws_size >= need) {
        const int total8 = n * C_CH / 8;
        convert_feat_kernel<<<(total8 + 255) / 256, 256, 0, stream>>>(
            feat, featb, total8);
        conv_mfma_kernel<<<CONV_GRID, 256, 0, stream>>>(
            featb, wbf, nbr, out, stats, n);
    } else {
        conv_mfma_f32_kernel<<<CONV_GRID, 256, 0, stream>>>(
            feat, wbf, nbr, out, stats, n);
    }

    const int total4 = n * C_CH / 4;
    bn_apply_kernel<<<(total4 + 255) / 256, 256, 0, stream>>>(
        out, stats, gamma, beta, 1.0f / (float)n, total4);
}